// Round 6
// baseline (191.841 us; speedup 1.0000x reference)
//
#include <hip/hip_runtime.h>
#include <math.h>

// Problem constants (fixed by setup_inputs)
#define CIN      8
#define H_IN     100
#define W_IN     136
#define NPIX     (H_IN * W_IN)       // 13600
#define OH       (2 * H_IN)          // 200
#define OW       (2 * W_IN)          // 272
#define ONPIX    (OH * OW)           // 54400
#define NPARAMS  169
#define EPSV     1e-5f
#define NSLICE   5                   // row-slices per instance (20 rows each)
#define ROWS_PER 20
#define KG4      34                  // 136/4 col-groups of 4 src px
#define KGROUPS  34                  // 272/8 output col-groups
#define TASKS_B  (ROWS_PER * KGROUPS)  // 680 phase-B tasks per slice
#define BLK      128

// param layout: w0[8][10] @0, w1[8][8] @80, w2[8] @144, b0 @152, b1 @160, b2 @168

__device__ __forceinline__ float sigmoidf_fast(float x) {
    float e = __expf(-x);
    return __builtin_amdgcn_rcpf(1.f + e);
}

// Session ledger:
//  R1: gt->LDS prefetch       -> +11us (vmcnt in-order drain stalls phase A)
//  R2: (256,5) occupancy bump -> neutral (stall synchronous across waves)
//  R3: 2-px reg ping-pong     -> +4us (task overhead > latency hidden)
//  R4: kernel split A/B       -> +30us (block stagger already overlaps phases
//      device-wide; dispatch boundary serializes + 54MB extra traffic)
//  R5: DO_PAIR weight-walk    -> -2.4us (scalar-weight traffic real but minor)
// This round: CU-LEVEL PHASE MIXING. Kernel time ~45us vs ~20us ideal
// (14us A-VALU + 3us B-VALU, 17us gt stream overlappable) => ~half is
// phase-synchronized stall: 256-thr blocks x 4/CU march in lockstep through
// compute-A (HBM idle) then storm HBM in B (VALU idle). Shrink blocks to 128
// threads x 8 blocks/CU (same 4 waves/SIMD): barriers sync 2 waves not 4,
// and 8 independent blocks per CU drift out of phase => A-FMA and B-loads
// co-resident on each SIMD. Per-px math/FMA order identical to R5.
__global__ __launch_bounds__(BLK, 4)
void mask_head_fused(const float* __restrict__ mask_feats,   // [N,8,100,136]
                     const float* __restrict__ params,       // [n,169]
                     const float* __restrict__ locs,         // [n,2]
                     const float* __restrict__ gt,           // [n,1,200,272]
                     const int*   __restrict__ im_inds,      // [n]
                     const int*   __restrict__ fpn_levels,   // [n]
                     float*       __restrict__ partials)     // [n*5][3]
{
    const int inst  = blockIdx.x / NSLICE;
    const int slice = blockIdx.x - inst * NSLICE;
    const int tid   = threadIdx.x;

    // src rows for this slice: max(20*slice-1,0) .. 20*slice+19
    const int r_start = (slice == 0) ? 0 : ROWS_PER * slice - 1;
    const int nrows   = (slice == 0) ? ROWS_PER : ROWS_PER + 1;
    const int ntask   = nrows * KG4;               // 680 or 714

    __shared__ float s_logit[(ROWS_PER + 1) * W_IN];   // 21*136*4 = 11424 B
    __shared__ float s_red[6];

    // Block-uniform weight pointer -> scalar K$ loads.
    const float* __restrict__ wp = params + (size_t)inst * NPARAMS;

    const int   im  = im_inds[inst];
    const int   lvl = fpn_levels[inst];
    const float inv_soi = exp2f(-(float)(3 + lvl));  // SOI = 8*2^lvl, exact
    const float lx = locs[inst * 2 + 0];
    const float ly = locs[inst * 2 + 1];
    const float dx8 = 8.f * inv_soi;

    const float* feat = mask_feats + (size_t)im * (CIN * NPIX);
    const int goff = r_start * W_IN;   // global pixel offset of local row 0

    // ---------------- Phase A: logits -> LDS ----------------
    // Task = 4 consecutive px in one row; weights walked once per 2 px
    // (DO_PAIR, R5). Invalid tail tasks skipped (execz).
    #pragma unroll 1
    for (int it = 0; it < 6; ++it) {
        const int t = it * BLK + tid;
        if (t < ntask) {
            const int r  = t / KG4;                    // local row
            const int k  = t - r * KG4;                // col-group
            const int lpx = r * W_IN + 4 * k;
            const float* fb = feat + (goff + lpx);

            // all 8 channel loads in flight together
            float4 f[8];
            #pragma unroll
            for (int c = 0; c < CIN; ++c)
                f[c] = *(const float4*)(fb + c * NPIX);

            float in0[4];
            in0[0] = (lx - (float)(32 * k + 4)) * inv_soi;
            in0[1] = in0[0] - dx8;
            in0[2] = in0[1] - dx8;
            in0[3] = in0[2] - dx8;
            const float in1 = (ly - (float)((r_start + r) * 8 + 4)) * inv_soi;

            float o4[4];

            // Per-px FMA order identical to the per-px macro (bit-identical
            // results); only interleaved between the two px of a pair.
#define DO_PAIR(J0, J1, CX, CY)                                               \
            {                                                                 \
                float a0[8], a1[8];                                           \
                _Pragma("unroll")                                             \
                for (int o = 0; o < 8; ++o) {                                 \
                    const float b = fmaf(wp[o * 10 + 1], in1, wp[152 + o]);   \
                    a0[o] = fmaf(wp[o * 10], in0[J0], b);                     \
                    a1[o] = fmaf(wp[o * 10], in0[J1], b);                     \
                }                                                             \
                _Pragma("unroll")                                             \
                for (int c = 0; c < 8; ++c) {                                 \
                    _Pragma("unroll")                                         \
                    for (int o = 0; o < 8; ++o) {                             \
                        const float w = wp[o * 10 + 2 + c];                   \
                        a0[o] = fmaf(w, f[c].CX, a0[o]);                      \
                        a1[o] = fmaf(w, f[c].CY, a1[o]);                      \
                    }                                                         \
                }                                                             \
                _Pragma("unroll")                                             \
                for (int o = 0; o < 8; ++o) {                                 \
                    a0[o] = fmaxf(a0[o], 0.f);                                \
                    a1[o] = fmaxf(a1[o], 0.f);                                \
                }                                                             \
                float acc0 = wp[168], acc1 = wp[168];                         \
                _Pragma("unroll")                                             \
                for (int o = 0; o < 8; ++o) {                                 \
                    float t0 = wp[160 + o], t1 = wp[160 + o];                 \
                    _Pragma("unroll")                                         \
                    for (int i = 0; i < 8; ++i) {                             \
                        const float w = wp[80 + o * 8 + i];                   \
                        t0 = fmaf(w, a0[i], t0);                              \
                        t1 = fmaf(w, a1[i], t1);                              \
                    }                                                         \
                    acc0 = fmaf(wp[144 + o], fmaxf(t0, 0.f), acc0);          \
                    acc1 = fmaf(wp[144 + o], fmaxf(t1, 0.f), acc1);          \
                }                                                             \
                o4[J0] = acc0;                                                \
                o4[J1] = acc1;                                                \
            }

            DO_PAIR(0, 1, x, y)
            DO_PAIR(2, 3, z, w)
#undef DO_PAIR

            float4 ov = {o4[0], o4[1], o4[2], o4[3]};
            *(float4*)(s_logit + lpx) = ov;   // 16B-aligned
        }
    }

    __syncthreads();

    // ---------------- Phase B: structured x2 upsample + sigmoid + dice ----------
    // Output row 2p   = avg(src row p-1, src row p)   (p=0: src row 0)
    // Output row 2p+1 = src row p
    // Output cols: o[2j]=avg of adjacent src cols, o[2j+1]=src col (left clamp)
    float inter = 0.f, ssum = 0.f, tsum = 0.f;
    const float* gtp = gt + (size_t)inst * ONPIX;
    const int pair_base = ROWS_PER * slice;

    #pragma unroll 1
    for (int base = 0; base < TASKS_B; base += BLK) {
        const int task = base + tid;
        if (task < TASKS_B) {
            const int pl = task / KGROUPS;
            const int k  = task - pl * KGROUPS;
            const int pg = pair_base + pl;
            const int er = pg - r_start;                       // exact src row (local)
            const int pr = (pg > 0 ? pg - 1 : 0) - r_start;    // prev src row (local)
            const float* E = s_logit + er * W_IN;
            const float* P = s_logit + pr * W_IN;
            const int c0  = 4 * k;
            const int cm1 = (k > 0) ? c0 - 1 : 0;

            // issue all loads upfront (gt first: longest latency)
            const float* g0 = gtp + (size_t)(2 * pg) * OW + 8 * k;
            const float4 ga = *(const float4*)(g0);            // avg row, cols 0-3
            const float4 gb = *(const float4*)(g0 + 4);        // avg row, cols 4-7
            const float4 gc = *(const float4*)(g0 + OW);       // exact row, cols 0-3
            const float4 gd = *(const float4*)(g0 + OW + 4);   // exact row, cols 4-7
            const float4 e4 = *(const float4*)(E + c0);
            const float  em = E[cm1];
            const float4 p4 = *(const float4*)(P + c0);
            const float  pm = P[cm1];

            const float ecur[4] = {e4.x, e4.y, e4.z, e4.w};
            const float pcur[4] = {p4.x, p4.y, p4.z, p4.w};
            const float gav[8] = {ga.x, ga.y, ga.z, ga.w, gb.x, gb.y, gb.z, gb.w};
            const float gex[8] = {gc.x, gc.y, gc.z, gc.w, gd.x, gd.y, gd.z, gd.w};

            float Se_prev = em;
            float Sa_prev = 0.5f * (em + pm);
            #pragma unroll
            for (int j = 0; j < 4; ++j) {
                const float Se = ecur[j];
                const float Sa = 0.5f * (ecur[j] + pcur[j]);
                {
                    float s = sigmoidf_fast(0.5f * (Sa_prev + Sa));
                    float t2 = gav[2 * j];
                    inter = fmaf(s, t2, inter); ssum = fmaf(s, s, ssum); tsum = fmaf(t2, t2, tsum);
                    s = sigmoidf_fast(Sa);
                    t2 = gav[2 * j + 1];
                    inter = fmaf(s, t2, inter); ssum = fmaf(s, s, ssum); tsum = fmaf(t2, t2, tsum);
                }
                {
                    float s = sigmoidf_fast(0.5f * (Se_prev + Se));
                    float t2 = gex[2 * j];
                    inter = fmaf(s, t2, inter); ssum = fmaf(s, s, ssum); tsum = fmaf(t2, t2, tsum);
                    s = sigmoidf_fast(Se);
                    t2 = gex[2 * j + 1];
                    inter = fmaf(s, t2, inter); ssum = fmaf(s, s, ssum); tsum = fmaf(t2, t2, tsum);
                }
                Se_prev = Se;
                Sa_prev = Sa;
            }
        }
    }

    // block reduction (2 waves of 64)
    #pragma unroll
    for (int off = 32; off > 0; off >>= 1) {
        inter += __shfl_down(inter, off, 64);
        ssum  += __shfl_down(ssum,  off, 64);
        tsum  += __shfl_down(tsum,  off, 64);
    }
    const int wid = tid >> 6;
    if ((tid & 63) == 0) {
        s_red[wid * 3 + 0] = inter;
        s_red[wid * 3 + 1] = ssum;
        s_red[wid * 3 + 2] = tsum;
    }
    __syncthreads();
    if (tid == 0) {
        partials[blockIdx.x * 3 + 0] = s_red[0] + s_red[3];
        partials[blockIdx.x * 3 + 1] = s_red[1] + s_red[4];
        partials[blockIdx.x * 3 + 2] = s_red[2] + s_red[5];
    }
}

__global__ __launch_bounds__(512)
void loss_mean_kernel(const float* __restrict__ partials, float* __restrict__ out, int n)
{
    __shared__ float s_red[8];
    float v = 0.f;
    for (int i = threadIdx.x; i < n; i += 512) {
        float I = 0.f, S = 0.f, T = 0.f;
        #pragma unroll
        for (int s = 0; s < NSLICE; ++s) {
            const float* p = partials + (size_t)(i * NSLICE + s) * 3;
            I += p[0];
            S += p[1];
            T += p[2];
        }
        v += 1.f - 2.f * I / (S + T + EPSV);
    }
    #pragma unroll
    for (int off = 32; off > 0; off >>= 1) v += __shfl_down(v, off, 64);
    const int wid = threadIdx.x >> 6;
    if ((threadIdx.x & 63) == 0) s_red[wid] = v;
    __syncthreads();
    if (threadIdx.x == 0) {
        float s = 0.f;
        #pragma unroll
        for (int w = 0; w < 8; ++w) s += s_red[w];
        out[0] = s / (float)n;
    }
}

extern "C" void kernel_launch(void* const* d_in, const int* in_sizes, int n_in,
                              void* d_out, int out_size, void* d_ws, size_t ws_size,
                              hipStream_t stream)
{
    const float* mask_feats = (const float*)d_in[0];
    const float* params     = (const float*)d_in[1];
    const float* locs       = (const float*)d_in[2];
    const float* gt         = (const float*)d_in[3];
    const int*   im_inds    = (const int*)d_in[4];
    const int*   fpn_levels = (const int*)d_in[5];
    // d_in[6] = mask_feat_stride (always 8 for this problem)

    const int n = in_sizes[4];          // 500 instances
    float* partials = (float*)d_ws;     // n*NSLICE*3 floats

    mask_head_fused<<<n * NSLICE, BLK, 0, stream>>>(mask_feats, params, locs, gt,
                                                    im_inds, fpn_levels, partials);
    loss_mean_kernel<<<1, 512, 0, stream>>>(partials, (float*)d_out, n);
}

// Round 7
// 180.531 us; speedup vs baseline: 1.0627x; 1.0627x over previous
//
#include <hip/hip_runtime.h>
#include <math.h>

// Problem constants (fixed by setup_inputs)
#define CIN      8
#define H_IN     100
#define W_IN     136
#define NPIX     (H_IN * W_IN)       // 13600
#define OH       (2 * H_IN)          // 200
#define OW       (2 * W_IN)          // 272
#define ONPIX    (OH * OW)           // 54400
#define NPARAMS  169
#define EPSV     1e-5f
#define NSLICE   4                   // row-slices per instance
#define KG4      34                  // 136/4 col-groups of 4 src px
#define KGROUPS  34                  // 272/8 output col-groups
#define TASKS_B  (25 * KGROUPS)      // 850 phase-B tasks per slice

// param layout: w0[8][10] @0, w1[8][8] @80, w2[8] @144, b0 @152, b1 @160, b2 @168

__device__ __forceinline__ float sigmoidf_fast(float x) {
    float e = __expf(-x);
    return __builtin_amdgcn_rcpf(1.f + e);
}

// Session ledger:
//  R1: gt->LDS prefetch        -> +11us (vmcnt in-order drain stalls phase A)
//  R2: (256,5) occupancy bump  -> neutral (stall synchronous across waves)
//  R3: 2-px reg ping-pong in A -> +4us (task overhead > latency hidden) [B
//      ping-pong was bundled in; untested alone]
//  R4: kernel split A/B        -> +30us (block stagger already overlaps
//      phases device-wide; dispatch boundary serializes + 54MB traffic)
//  R5: DO_PAIR weight-walk     -> -2.4us BEST=179.8 (scalar-weight traffic
//      real but minor)
//  R6: 128-thr blocks (128,4)  -> +12us; VGPR fell to 40 -> compiler
//      serialized f[8] loads. Counters: VALUBusy 60%, FETCH at 875GB/s ->
//      phase B is LATENCY-bound (4 waves x 220cyc < 900cyc HBM round-trip).
// This round: R5 verbatim EXCEPT phase-B register ping-pong (single
// variable): first gt-load set issued pre-barrier (latency hides under the
// barrier drain), then load(t+1) before compute(t). In-order vmcnt means
// compute(t) waits only on the older buffer; younger stays in flight.
__global__ __launch_bounds__(256, 4)
void mask_head_fused(const float* __restrict__ mask_feats,   // [N,8,100,136]
                     const float* __restrict__ params,       // [n,169]
                     const float* __restrict__ locs,         // [n,2]
                     const float* __restrict__ gt,           // [n,1,200,272]
                     const int*   __restrict__ im_inds,      // [n]
                     const int*   __restrict__ fpn_levels,   // [n]
                     float*       __restrict__ partials)     // [n*4][3]
{
    const int inst  = blockIdx.x >> 2;
    const int slice = blockIdx.x & 3;
    const int tid   = threadIdx.x;

    // src rows for this slice: max(25*slice-1,0) .. 25*slice+24
    const int r_start = (slice == 0) ? 0 : 25 * slice - 1;
    const int nrows   = (slice == 0) ? 25 : 26;
    const int ntask   = nrows * KG4;               // 850 or 884

    __shared__ float s_logit[26 * W_IN];           // 14144 B
    __shared__ float s_red[12];

    // Block-uniform weight pointer -> scalar K$ loads.
    const float* __restrict__ wp = params + (size_t)inst * NPARAMS;

    const int   im  = im_inds[inst];
    const int   lvl = fpn_levels[inst];
    const float inv_soi = exp2f(-(float)(3 + lvl));  // SOI = 8*2^lvl, exact
    const float lx = locs[inst * 2 + 0];
    const float ly = locs[inst * 2 + 1];
    const float dx8 = 8.f * inv_soi;

    const float* feat = mask_feats + (size_t)im * (CIN * NPIX);
    const int goff = r_start * W_IN;   // global pixel offset of local row 0

    // ---------------- Phase A: logits -> LDS (R5 verbatim) ----------------
    #pragma unroll 1
    for (int it = 0; it < 4; ++it) {
        const int t = it * 256 + tid;
        if (t < ntask) {
            const int r  = t / KG4;                    // local row
            const int k  = t - r * KG4;                // col-group
            const int lpx = r * W_IN + 4 * k;
            const float* fb = feat + (goff + lpx);

            // all 8 channel loads in flight together
            float4 f[8];
            #pragma unroll
            for (int c = 0; c < CIN; ++c)
                f[c] = *(const float4*)(fb + c * NPIX);

            float in0[4];
            in0[0] = (lx - (float)(32 * k + 4)) * inv_soi;
            in0[1] = in0[0] - dx8;
            in0[2] = in0[1] - dx8;
            in0[3] = in0[2] - dx8;
            const float in1 = (ly - (float)((r_start + r) * 8 + 4)) * inv_soi;

            float o4[4];

            // Per-px FMA order identical to the per-px macro (bit-identical
            // results); only interleaved between the two px of a pair.
#define DO_PAIR(J0, J1, CX, CY)                                               \
            {                                                                 \
                float a0[8], a1[8];                                           \
                _Pragma("unroll")                                             \
                for (int o = 0; o < 8; ++o) {                                 \
                    const float b = fmaf(wp[o * 10 + 1], in1, wp[152 + o]);   \
                    a0[o] = fmaf(wp[o * 10], in0[J0], b);                     \
                    a1[o] = fmaf(wp[o * 10], in0[J1], b);                     \
                }                                                             \
                _Pragma("unroll")                                             \
                for (int c = 0; c < 8; ++c) {                                 \
                    _Pragma("unroll")                                         \
                    for (int o = 0; o < 8; ++o) {                             \
                        const float w = wp[o * 10 + 2 + c];                   \
                        a0[o] = fmaf(w, f[c].CX, a0[o]);                      \
                        a1[o] = fmaf(w, f[c].CY, a1[o]);                      \
                    }                                                         \
                }                                                             \
                _Pragma("unroll")                                             \
                for (int o = 0; o < 8; ++o) {                                 \
                    a0[o] = fmaxf(a0[o], 0.f);                                \
                    a1[o] = fmaxf(a1[o], 0.f);                                \
                }                                                             \
                float acc0 = wp[168], acc1 = wp[168];                         \
                _Pragma("unroll")                                             \
                for (int o = 0; o < 8; ++o) {                                 \
                    float t0 = wp[160 + o], t1 = wp[160 + o];                 \
                    _Pragma("unroll")                                         \
                    for (int i = 0; i < 8; ++i) {                             \
                        const float w = wp[80 + o * 8 + i];                   \
                        t0 = fmaf(w, a0[i], t0);                              \
                        t1 = fmaf(w, a1[i], t1);                              \
                    }                                                         \
                    acc0 = fmaf(wp[144 + o], fmaxf(t0, 0.f), acc0);          \
                    acc1 = fmaf(wp[144 + o], fmaxf(t1, 0.f), acc1);          \
                }                                                             \
                o4[J0] = acc0;                                                \
                o4[J1] = acc1;                                                \
            }

            DO_PAIR(0, 1, x, y)
            DO_PAIR(2, 3, z, w)
#undef DO_PAIR

            float4 ov = {o4[0], o4[1], o4[2], o4[3]};
            *(float4*)(s_logit + lpx) = ov;   // 16B-aligned
        }
    }

    // ---------------- Phase B: x2 upsample + sigmoid + dice (ping-pong) -----
    float inter = 0.f, ssum = 0.f, tsum = 0.f;
    const float* gtp = gt + (size_t)inst * ONPIX;
    const int pair_base = 25 * slice;

    auto loadgt = [&](float4 (&g)[4], int task) {
        const int pl = task / KGROUPS;
        const int k  = task - pl * KGROUPS;
        const int pg = pair_base + pl;
        const float* g0 = gtp + (size_t)(2 * pg) * OW + 8 * k;
        g[0] = *(const float4*)(g0);            // avg row, cols 0-3
        g[1] = *(const float4*)(g0 + 4);        // avg row, cols 4-7
        g[2] = *(const float4*)(g0 + OW);       // exact row, cols 0-3
        g[3] = *(const float4*)(g0 + OW + 4);   // exact row, cols 4-7
    };

    auto computeB = [&](const float4 (&g)[4], int task) {
        const int pl = task / KGROUPS;
        const int k  = task - pl * KGROUPS;
        const int pg = pair_base + pl;
        const int er = pg - r_start;                       // exact src row (local)
        const int pr = (pg > 0 ? pg - 1 : 0) - r_start;    // prev src row (local)
        const float* E = s_logit + er * W_IN;
        const float* P = s_logit + pr * W_IN;
        const int c0  = 4 * k;
        const int cm1 = (k > 0) ? c0 - 1 : 0;

        const float4 e4 = *(const float4*)(E + c0);
        const float  em = E[cm1];
        const float4 p4 = *(const float4*)(P + c0);
        const float  pm = P[cm1];

        const float ecur[4] = {e4.x, e4.y, e4.z, e4.w};
        const float pcur[4] = {p4.x, p4.y, p4.z, p4.w};
        const float gav[8] = {g[0].x, g[0].y, g[0].z, g[0].w,
                              g[1].x, g[1].y, g[1].z, g[1].w};
        const float gex[8] = {g[2].x, g[2].y, g[2].z, g[2].w,
                              g[3].x, g[3].y, g[3].z, g[3].w};

        float Se_prev = em;
        float Sa_prev = 0.5f * (em + pm);
        #pragma unroll
        for (int j = 0; j < 4; ++j) {
            const float Se = ecur[j];
            const float Sa = 0.5f * (ecur[j] + pcur[j]);
            {
                float s = sigmoidf_fast(0.5f * (Sa_prev + Sa));
                float t2 = gav[2 * j];
                inter = fmaf(s, t2, inter); ssum = fmaf(s, s, ssum); tsum = fmaf(t2, t2, tsum);
                s = sigmoidf_fast(Sa);
                t2 = gav[2 * j + 1];
                inter = fmaf(s, t2, inter); ssum = fmaf(s, s, ssum); tsum = fmaf(t2, t2, tsum);
            }
            {
                float s = sigmoidf_fast(0.5f * (Se_prev + Se));
                float t2 = gex[2 * j];
                inter = fmaf(s, t2, inter); ssum = fmaf(s, s, ssum); tsum = fmaf(t2, t2, tsum);
                s = sigmoidf_fast(Se);
                t2 = gex[2 * j + 1];
                inter = fmaf(s, t2, inter); ssum = fmaf(s, s, ssum); tsum = fmaf(t2, t2, tsum);
            }
            Se_prev = Se;
            Sa_prev = Sa;
        }
    };

    {
        float4 gA[4], gB[4];
        const int t0 = tid;                 // always valid (tid < 256 <= 850)
        // issued BEFORE the barrier: ~900cyc HBM latency hides under the
        // barrier drain (waves wait on stragglers anyway). Loads go to
        // registers, so phase A's LDS consistency is untouched.
        loadgt(gA, t0);

        __syncthreads();

        const int t1 = t0 + 256;
        const int t2 = t0 + 512;
        const int t3 = t0 + 768;
        if (t1 < TASKS_B) loadgt(gB, t1);
        computeB(gA, t0);
        if (t2 < TASKS_B) loadgt(gA, t2);
        if (t1 < TASKS_B) computeB(gB, t1);
        if (t3 < TASKS_B) loadgt(gB, t3);
        if (t2 < TASKS_B) computeB(gA, t2);
        if (t3 < TASKS_B) computeB(gB, t3);
    }

    // block reduction (4 waves of 64)
    #pragma unroll
    for (int off = 32; off > 0; off >>= 1) {
        inter += __shfl_down(inter, off, 64);
        ssum  += __shfl_down(ssum,  off, 64);
        tsum  += __shfl_down(tsum,  off, 64);
    }
    const int wid = tid >> 6;
    if ((tid & 63) == 0) {
        s_red[wid * 3 + 0] = inter;
        s_red[wid * 3 + 1] = ssum;
        s_red[wid * 3 + 2] = tsum;
    }
    __syncthreads();
    if (tid == 0) {
        float I = 0.f, S = 0.f, T = 0.f;
        #pragma unroll
        for (int w = 0; w < 4; ++w) {
            I += s_red[w * 3 + 0];
            S += s_red[w * 3 + 1];
            T += s_red[w * 3 + 2];
        }
        partials[blockIdx.x * 3 + 0] = I;
        partials[blockIdx.x * 3 + 1] = S;
        partials[blockIdx.x * 3 + 2] = T;
    }
}

__global__ __launch_bounds__(512)
void loss_mean_kernel(const float* __restrict__ partials, float* __restrict__ out, int n)
{
    __shared__ float s_red[8];
    float v = 0.f;
    for (int i = threadIdx.x; i < n; i += 512) {
        float I = 0.f, S = 0.f, T = 0.f;
        #pragma unroll
        for (int s = 0; s < NSLICE; ++s) {
            const float* p = partials + (size_t)(i * NSLICE + s) * 3;
            I += p[0];
            S += p[1];
            T += p[2];
        }
        v += 1.f - 2.f * I / (S + T + EPSV);
    }
    #pragma unroll
    for (int off = 32; off > 0; off >>= 1) v += __shfl_down(v, off, 64);
    const int wid = threadIdx.x >> 6;
    if ((threadIdx.x & 63) == 0) s_red[wid] = v;
    __syncthreads();
    if (threadIdx.x == 0) {
        float s = 0.f;
        #pragma unroll
        for (int w = 0; w < 8; ++w) s += s_red[w];
        out[0] = s / (float)n;
    }
}

extern "C" void kernel_launch(void* const* d_in, const int* in_sizes, int n_in,
                              void* d_out, int out_size, void* d_ws, size_t ws_size,
                              hipStream_t stream)
{
    const float* mask_feats = (const float*)d_in[0];
    const float* params     = (const float*)d_in[1];
    const float* locs       = (const float*)d_in[2];
    const float* gt         = (const float*)d_in[3];
    const int*   im_inds    = (const int*)d_in[4];
    const int*   fpn_levels = (const int*)d_in[5];
    // d_in[6] = mask_feat_stride (always 8 for this problem)

    const int n = in_sizes[4];          // 500 instances
    float* partials = (float*)d_ws;     // n*NSLICE*3 floats

    mask_head_fused<<<n * NSLICE, 256, 0, stream>>>(mask_feats, params, locs, gt,
                                                    im_inds, fpn_levels, partials);
    loss_mean_kernel<<<1, 512, 0, stream>>>(partials, (float*)d_out, n);
}